// Round 3
// baseline (261.749 us; speedup 1.0000x reference)
//
#include <hip/hip_runtime.h>
#include <hip/hip_bf16.h>

// ---------------- problem constants ----------------
#define BATCH   32768
#define DIM     512
#define H1N     128
#define H2N     256
#define NSUB    20
#define HID     32
#define NCLS    100
#define NHID    640            // NSUB*HID
#define TOTALP  19716          // 512*32 + 32 + 32*100 + 100
#define NPAR    394320         // NSUB*TOTALP
#define WS1P    16384
#define WS1B1   16416          // WS1+BS1
#define WS2END  19616          // WS1+BS1+WS2

// ---------------- ws layout (float units) ----------------
#define OFF_PART 0              // 512*512 partial col sums
#define OFF_H    262144         // 256 f32 hypernet h
#define OFF_W    262400         // 32 f32 softmax(ens_w)
#define OFF_B1   262432         // 640 f32
#define OFF_BE   263072         // 128 f32
#define OFF_B2R  263200         // 2000 f32 raw b2
#define OFF_W1B  265200         // bf16 640*512   (163840 f32 slots)
#define OFF_W2B  429040         // bf16 128*640   (40960 f32 slots)
#define OFF_XB   470000         // bf16 32768*512 (8388608 f32 slots)
#define OFF_HH   8858608        // bf16 32768*640 (10485760 f32 slots)

typedef __attribute__((ext_vector_type(8))) short short8;
typedef __attribute__((ext_vector_type(4))) float f32x4;

static __device__ inline unsigned short f2bf(float f) {
    __hip_bfloat16 h = __float2bfloat16(f);
    return *reinterpret_cast<unsigned short*>(&h);
}

static __device__ __forceinline__ void gload16(const void* g, void* l) {
    __builtin_amdgcn_global_load_lds(
        (const __attribute__((address_space(1))) void*)g,
        (__attribute__((address_space(3))) void*)l, 16, 0, 0);
}

// ---------------- K1: partial column sums + bf16 convert of x ----------------
// 512 blocks x 64 rows. Thread t<128 handles even rows cols t*4..+3 (float4),
// t>=128 odd rows. LDS-combine the two parity partial sets at the end.
__global__ __launch_bounds__(256) void k1_colsum(const float* __restrict__ x,
                                                 float* __restrict__ F) {
    __shared__ float sP[DIM];
    int t = threadIdx.x, bid = blockIdx.x;
    int par = t >> 7;            // 0 or 1
    int c4 = (t & 127) * 4;
    const float* xb = x + (size_t)bid * 64 * DIM;
    unsigned short* ob = (unsigned short*)(F + OFF_XB) + (size_t)bid * 64 * DIM;
    float4 acc = make_float4(0.f, 0.f, 0.f, 0.f);
    #pragma unroll 4
    for (int i = 0; i < 32; ++i) {
        int r = 2 * i + par;
        float4 v = *(const float4*)(xb + r * DIM + c4);
        acc.x += v.x; acc.y += v.y; acc.z += v.z; acc.w += v.w;
        ushort4 u;
        u.x = f2bf(v.x); u.y = f2bf(v.y); u.z = f2bf(v.z); u.w = f2bf(v.w);
        *(ushort4*)(ob + r * DIM + c4) = u;
    }
    if (par == 0) *(float4*)(sP + c4) = acc;
    __syncthreads();
    if (par == 1) {
        float4 p = *(const float4*)(sP + c4);
        p.x += acc.x; p.y += acc.y; p.z += acc.z; p.w += acc.w;
        *(float4*)(F + OFF_PART + bid * DIM + c4) = p;
    }
}

// ---------------- K2: hypernet trunk (1 block) ----------------
__global__ __launch_bounds__(256) void k2_hyper(
    const float* __restrict__ Wh1, const float* __restrict__ bh1,
    const float* __restrict__ g1,  const float* __restrict__ be1,
    const float* __restrict__ Wh2, const float* __restrict__ bh2,
    const float* __restrict__ g2,  const float* __restrict__ be2,
    const float* __restrict__ ensw, float* __restrict__ F)
{
    __shared__ __align__(16) float sctx[DIM];
    __shared__ __align__(16) float sh1[H1N];
    __shared__ __align__(16) float sh2[H2N];
    int t = threadIdx.x;

    for (int c = t; c < DIM; c += 256) {
        float s = 0.f;
        for (int b = 0; b < 512; ++b) s += F[OFF_PART + b * DIM + c];
        sctx[c] = s * (1.0f / (float)BATCH);
    }
    __syncthreads();

    // layer 1
    if (t < H1N) {
        float v = bh1[t];
        const float4* w = (const float4*)(Wh1 + t * DIM);
        for (int k = 0; k < DIM / 4; ++k) {
            float4 ww = w[k]; float4 c = *(const float4*)(sctx + k * 4);
            v += ww.x * c.x + ww.y * c.y + ww.z * c.z + ww.w * c.w;
        }
        sh1[t] = v;
    }
    __syncthreads();
    {
        float mu = 0.f;
        for (int k = 0; k < H1N; ++k) mu += sh1[k];
        mu *= (1.0f / H1N);
        float var = 0.f;
        for (int k = 0; k < H1N; ++k) { float d = sh1[k] - mu; var += d * d; }
        var *= (1.0f / H1N);
        float inv = rsqrtf(var + 1e-5f);
        __syncthreads();
        if (t < H1N) {
            float v = (sh1[t] - mu) * inv * g1[t] + be1[t];
            sh1[t] = fmaxf(v, 0.f);
        }
        __syncthreads();
    }

    // layer 2
    {
        float v = bh2[t];
        const float4* w = (const float4*)(Wh2 + t * H1N);
        for (int k = 0; k < H1N / 4; ++k) {
            float4 ww = w[k]; float4 c = *(const float4*)(sh1 + k * 4);
            v += ww.x * c.x + ww.y * c.y + ww.z * c.z + ww.w * c.w;
        }
        sh2[t] = v;
    }
    __syncthreads();
    {
        float mu = 0.f;
        for (int k = 0; k < H2N; ++k) mu += sh2[k];
        mu *= (1.0f / H2N);
        float var = 0.f;
        for (int k = 0; k < H2N; ++k) { float d = sh2[k] - mu; var += d * d; }
        var *= (1.0f / H2N);
        float inv = rsqrtf(var + 1e-5f);
        float v = (sh2[t] - mu) * inv * g2[t] + be2[t];
        F[OFF_H + t] = fmaxf(v, 0.f);
    }

    if (t == 0) {
        float m = -1e30f;
        for (int s = 0; s < NSUB; ++s) m = fmaxf(m, ensw[s]);
        float sum = 0.f, e[NSUB];
        for (int s = 0; s < NSUB; ++s) { e[s] = __expf(ensw[s] - m); sum += e[s]; }
        for (int s = 0; s < NSUB; ++s) F[OFF_W + s] = e[s] / sum;
    }
}

// ---------------- K3: params GEMV fused with pack/convert ----------------
// 8 lanes per row, 8 rows per wave-task. Each lane: 32 contiguous floats of
// its row (8x dwordx4 in flight), 3-round shfl_xor reduce. Grid-stride.
#define K3TASKS (NPAR / 8)     // 49290
__global__ __launch_bounds__(256) void k3_gemv(
    const float* __restrict__ Wh3, const float* __restrict__ bh3, float* __restrict__ F)
{
    int t = threadIdx.x;
    int lane = t & 63;
    int sub = lane & 7;          // position within row
    int wgid = blockIdx.x * 4 + (t >> 6);
    int nw = gridDim.x * 4;

    // h segment for this lane (32 floats, fixed)
    float4 h[8];
    #pragma unroll
    for (int j = 0; j < 8; ++j)
        h[j] = *(const float4*)(F + OFF_H + sub * 32 + j * 4);

    __hip_bfloat16* W1B = (__hip_bfloat16*)(F + OFF_W1B);
    __hip_bfloat16* W2B = (__hip_bfloat16*)(F + OFF_W2B);

    for (int task = wgid; task < K3TASKS; task += nw) {
        int row = task * 8 + (lane >> 3);
        const float* wp = Wh3 + (size_t)row * 256 + sub * 32;
        float4 w[8];
        #pragma unroll
        for (int j = 0; j < 8; ++j) w[j] = *(const float4*)(wp + j * 4);
        float d = 0.f;
        #pragma unroll
        for (int j = 0; j < 8; ++j)
            d += w[j].x * h[j].x + w[j].y * h[j].y + w[j].z * h[j].z + w[j].w * h[j].w;
        d += __shfl_xor(d, 1);
        d += __shfl_xor(d, 2);
        d += __shfl_xor(d, 4);
        if (sub == 0) {
            float val = d + bh3[row];
            int s = row / TOTALP;
            int r = row - s * TOTALP;
            if (r < WS1P) {
                int hh = r >> 9, k = r & 511;
                W1B[(s * HID + hh) * DIM + k] = __float2bfloat16(val);
            } else if (r < WS1B1) {
                F[OFF_B1 + s * HID + (r - WS1P)] = val;
            } else if (r < WS2END) {
                int q = r - WS1B1; int c = q >> 5, hh = q & 31;
                float ws = F[OFF_W + s];
                W2B[c * NHID + s * HID + hh] = __float2bfloat16(ws * val);
            } else {
                F[OFF_B2R + s * NCLS + (r - WS2END)] = val;
            }
        }
    }
}

// ---------------- K4: b2 ensemble reduce ----------------
// W2B pad rows (100..127) stay at ws poison: finite bf16, masked at C-store.
__global__ __launch_bounds__(128) void k4_be(float* __restrict__ F) {
    int t = threadIdx.x;
    float b = 0.f;
    if (t < NCLS)
        for (int s = 0; s < NSUB; ++s)
            b += F[OFF_W + s] * F[OFF_B2R + s * NCLS + t];
    F[OFF_BE + t] = b;
}

// ---------------- K5: MFMA bf16 GEMM, C = act(A @ Bw^T + bias) ----------------
// BM = MR*64 rows per block, BN = 128, BK = 64. global_load_lds staging with
// pre-swizzled global source (linear LDS dest), XOR-swizzled ds_read.
// EPI=0: C bf16 ld 640, relu.  EPI=1: C f32 ld 100, col<100 mask.
template<int EPI, int MR>
__global__ __launch_bounds__(256) void gemm_k(
    const __hip_bfloat16* __restrict__ A, const __hip_bfloat16* __restrict__ Bw,
    const float* __restrict__ bias, void* __restrict__ Cp, int K, int lda, int nBN)
{
    __shared__ __align__(16) unsigned char sA[MR * 64 * 128];
    __shared__ __align__(16) unsigned char sB[128 * 128];
    const int t = threadIdx.x;
    // XCD-chunked swizzle (grid divisible by 8)
    int bid = blockIdx.x;
    const int cpx = gridDim.x >> 3;
    bid = (bid & 7) * cpx + (bid >> 3);
    const int bm = bid / nBN, bn = bid % nBN;
    const int Row0 = bm * (MR * 64), Col0 = bn * 128;
    const int wid = t >> 6, lane = t & 63;
    const int l16 = lane & 15, lq = lane >> 4;

    f32x4 acc[MR][8];
    #pragma unroll
    for (int a = 0; a < MR; ++a)
        #pragma unroll
        for (int b = 0; b < 8; ++b)
            acc[a][b] = (f32x4){0.f, 0.f, 0.f, 0.f};

    for (int kc = 0; kc < K; kc += 64) {
        __syncthreads();
        // A tile: MR*64 rows x 64 k, linear LDS, inverse-swizzled global source
        #pragma unroll
        for (int i = 0; i < MR * 2; ++i) {
            int cidx = wid * (MR * 2) + i;
            int ul = cidx * 64 + lane;
            int row = ul >> 3, u = ul & 7;
            const __hip_bfloat16* src =
                A + (size_t)(Row0 + row) * lda + kc + ((u ^ (row & 7)) << 3);
            gload16(src, sA + cidx * 1024);
        }
        // B tile: 128 rows x 64 k
        #pragma unroll
        for (int i = 0; i < 4; ++i) {
            int cidx = wid * 4 + i;
            int ul = cidx * 64 + lane;
            int row = ul >> 3, u = ul & 7;
            const __hip_bfloat16* src =
                Bw + (size_t)(Col0 + row) * K + kc + ((u ^ (row & 7)) << 3);
            gload16(src, sB + cidx * 1024);
        }
        __syncthreads();

        #pragma unroll
        for (int kk = 0; kk < 2; ++kk) {
            const int u = kk * 4 + lq;
            short8 af[MR], bfv[8];
            #pragma unroll
            for (int fm = 0; fm < MR; ++fm) {
                int row = wid * (MR * 16) + fm * 16 + l16;
                af[fm] = *(const short8*)(sA + row * 128 + ((u ^ (row & 7)) << 4));
            }
            #pragma unroll
            for (int fn = 0; fn < 8; ++fn) {
                int rw = fn * 16 + l16;
                bfv[fn] = *(const short8*)(sB + rw * 128 + ((u ^ (rw & 7)) << 4));
            }
            #pragma unroll
            for (int fm = 0; fm < MR; ++fm)
                #pragma unroll
                for (int fn = 0; fn < 8; ++fn)
                    acc[fm][fn] = __builtin_amdgcn_mfma_f32_16x16x32_bf16(
                        af[fm], bfv[fn], acc[fm][fn], 0, 0, 0);
        }
    }

    #pragma unroll
    for (int fm = 0; fm < MR; ++fm) {
        #pragma unroll
        for (int fn = 0; fn < 8; ++fn) {
            int gcol = Col0 + fn * 16 + l16;
            float bv = bias[gcol];
            #pragma unroll
            for (int r = 0; r < 4; ++r) {
                int grow = Row0 + wid * (MR * 16) + fm * 16 + lq * 4 + r;
                float v = acc[fm][fn][r] + bv;
                if (EPI == 0) {
                    v = fmaxf(v, 0.f);
                    ((__hip_bfloat16*)Cp)[(size_t)grow * NHID + gcol] = __float2bfloat16(v);
                } else {
                    if (gcol < NCLS)
                        ((float*)Cp)[(size_t)grow * NCLS + gcol] = v;
                }
            }
        }
    }
}

// ---------------- launch ----------------
extern "C" void kernel_launch(void* const* d_in, const int* in_sizes, int n_in,
                              void* d_out, int out_size, void* d_ws, size_t ws_size,
                              hipStream_t stream)
{
    const float* x    = (const float*)d_in[0];
    const float* Wh1  = (const float*)d_in[1];
    const float* bh1  = (const float*)d_in[2];
    const float* g1   = (const float*)d_in[3];
    const float* be1  = (const float*)d_in[4];
    const float* Wh2  = (const float*)d_in[5];
    const float* bh2  = (const float*)d_in[6];
    const float* g2   = (const float*)d_in[7];
    const float* be2  = (const float*)d_in[8];
    const float* Wh3  = (const float*)d_in[9];
    const float* bh3  = (const float*)d_in[10];
    const float* ensw = (const float*)d_in[11];
    float* F = (float*)d_ws;
    float* out = (float*)d_out;

    const __hip_bfloat16* XB  = (const __hip_bfloat16*)(F + OFF_XB);
    const __hip_bfloat16* W1B = (const __hip_bfloat16*)(F + OFF_W1B);
    const __hip_bfloat16* W2B = (const __hip_bfloat16*)(F + OFF_W2B);
    __hip_bfloat16* HH = (__hip_bfloat16*)(F + OFF_HH);

    k1_colsum<<<512, 256, 0, stream>>>(x, F);
    k2_hyper<<<1, 256, 0, stream>>>(Wh1, bh1, g1, be1, Wh2, bh2, g2, be2, ensw, F);
    k3_gemv<<<2048, 256, 0, stream>>>(Wh3, bh3, F);
    k4_be<<<1, 128, 0, stream>>>(F);
    // stage 1: HH = relu(xb @ W1all^T + b1all)   M=32768 N=640 K=512
    gemm_k<0, 2><<<(BATCH / 128) * 5, 256, 0, stream>>>(XB, W1B, F + OFF_B1, HH, 512, 512, 5);
    // stage 2: out = HH @ W2eff^T + beff         M=32768 N=128(pad) K=640
    gemm_k<1, 1><<<(BATCH / 64), 256, 0, stream>>>(HH, W2B, F + OFF_BE, out, 640, 640, 1);
}

// Round 4
// 243.510 us; speedup vs baseline: 1.0749x; 1.0749x over previous
//
#include <hip/hip_runtime.h>
#include <hip/hip_bf16.h>

// ---------------- problem constants ----------------
#define BATCH   32768
#define DIM     512
#define H1N     128
#define H2N     256
#define NSUB    20
#define HID     32
#define NCLS    100
#define NHID    640            // NSUB*HID
#define TOTALP  19716          // 512*32 + 32 + 32*100 + 100
#define NPAR    394320         // NSUB*TOTALP
#define WS1P    16384
#define WS1B1   16416          // WS1+BS1
#define WS2END  19616          // WS1+BS1+WS2

// ---------------- ws layout (float units) ----------------
#define OFF_CTX  0              // 512 f32 atomic col-sum accumulator (memset 0)
#define OFF_CNT  512            // counter (memset 0), padded
#define OFF_H    544            // 256 f32 hypernet h
#define OFF_W    800            // 32 f32 softmax(ens_w)
#define OFF_B1   832            // 640 f32
#define OFF_B2R  1472           // 2000 f32 raw b2
#define OFF_W1B  3472           // bf16 640*512   (163840 f32 slots)
#define OFF_W2B  167312         // bf16 128*640   (40960 f32 slots)
#define OFF_XB   208272         // bf16 32768*512 (8388608 f32 slots)
#define OFF_HH   8596880        // bf16 32768*640 (10485760 f32 slots)

typedef __attribute__((ext_vector_type(8))) short short8;
typedef __attribute__((ext_vector_type(4))) float f32x4;

static __device__ inline unsigned short f2bf(float f) {
    __hip_bfloat16 h = __float2bfloat16(f);
    return *reinterpret_cast<unsigned short*>(&h);
}

static __device__ __forceinline__ void gload16(const void* g, void* l) {
    __builtin_amdgcn_global_load_lds(
        (const __attribute__((address_space(1))) void*)g,
        (__attribute__((address_space(3))) void*)l, 16, 0, 0);
}

// ---------------- K1: col sums + bf16 convert + last-block hypernet trunk ----
__global__ __launch_bounds__(256) void k1_fused(
    const float* __restrict__ x,
    const float* __restrict__ Wh1, const float* __restrict__ bh1,
    const float* __restrict__ g1,  const float* __restrict__ be1,
    const float* __restrict__ Wh2, const float* __restrict__ bh2,
    const float* __restrict__ g2,  const float* __restrict__ be2,
    const float* __restrict__ ensw, float* __restrict__ F)
{
    __shared__ __align__(16) float sctx[DIM];
    __shared__ __align__(16) float sh1[H1N];
    __shared__ __align__(16) float sh2[H2N];
    __shared__ int sIsLast;

    int t = threadIdx.x, bid = blockIdx.x;
    const float* xb = x + (size_t)bid * 128 * DIM;
    unsigned short* ob = (unsigned short*)(F + OFF_XB) + (size_t)bid * 128 * DIM;
    float a0 = 0.f, a1 = 0.f;
    for (int r = 0; r < 128; ++r) {
        float2 v = *(const float2*)(xb + r * DIM + t * 2);
        a0 += v.x; a1 += v.y;
        ushort2 u; u.x = f2bf(v.x); u.y = f2bf(v.y);
        *(ushort2*)(ob + r * DIM + t * 2) = u;
    }
    atomicAdd(&F[OFF_CTX + 2 * t],     a0);
    atomicAdd(&F[OFF_CTX + 2 * t + 1], a1);
    __threadfence();
    __syncthreads();
    if (t == 0) {
        __threadfence();
        int old = atomicAdd((int*)(F + OFF_CNT), 1);
        sIsLast = (old == (int)gridDim.x - 1);
    }
    __syncthreads();
    if (!sIsLast) return;

    // ---- hypernet trunk (one block) ----
    for (int c = t; c < DIM; c += 256) {
        float s = __hip_atomic_load(&F[OFF_CTX + c], __ATOMIC_RELAXED,
                                    __HIP_MEMORY_SCOPE_AGENT);
        sctx[c] = s * (1.0f / (float)BATCH);
    }
    __syncthreads();

    // layer 1
    if (t < H1N) {
        float v = bh1[t];
        const float4* w = (const float4*)(Wh1 + t * DIM);
        for (int k = 0; k < DIM / 4; ++k) {
            float4 ww = w[k]; float4 c = *(const float4*)(sctx + k * 4);
            v += ww.x * c.x + ww.y * c.y + ww.z * c.z + ww.w * c.w;
        }
        sh1[t] = v;
    }
    __syncthreads();
    {
        float mu = 0.f;
        for (int k = 0; k < H1N; ++k) mu += sh1[k];
        mu *= (1.0f / H1N);
        float var = 0.f;
        for (int k = 0; k < H1N; ++k) { float d = sh1[k] - mu; var += d * d; }
        var *= (1.0f / H1N);
        float inv = rsqrtf(var + 1e-5f);
        __syncthreads();
        if (t < H1N) {
            float v = (sh1[t] - mu) * inv * g1[t] + be1[t];
            sh1[t] = fmaxf(v, 0.f);
        }
        __syncthreads();
    }

    // layer 2
    {
        float v = bh2[t];
        const float4* w = (const float4*)(Wh2 + t * H1N);
        for (int k = 0; k < H1N / 4; ++k) {
            float4 ww = w[k]; float4 c = *(const float4*)(sh1 + k * 4);
            v += ww.x * c.x + ww.y * c.y + ww.z * c.z + ww.w * c.w;
        }
        sh2[t] = v;
    }
    __syncthreads();
    {
        float mu = 0.f;
        for (int k = 0; k < H2N; ++k) mu += sh2[k];
        mu *= (1.0f / H2N);
        float var = 0.f;
        for (int k = 0; k < H2N; ++k) { float d = sh2[k] - mu; var += d * d; }
        var *= (1.0f / H2N);
        float inv = rsqrtf(var + 1e-5f);
        float v = (sh2[t] - mu) * inv * g2[t] + be2[t];
        F[OFF_H + t] = fmaxf(v, 0.f);
    }

    if (t == 0) {
        float m = -1e30f;
        for (int s = 0; s < NSUB; ++s) m = fmaxf(m, ensw[s]);
        float sum = 0.f, e[NSUB];
        for (int s = 0; s < NSUB; ++s) { e[s] = __expf(ensw[s] - m); sum += e[s]; }
        for (int s = 0; s < NSUB; ++s) F[OFF_W + s] = e[s] / sum;
    }
}

// ---------------- K3: params GEMV fused with pack/convert (wave per row) -----
__global__ __launch_bounds__(256) void k3_gemv(
    const float* __restrict__ Wh3, const float* __restrict__ bh3, float* __restrict__ F)
{
    int t = threadIdx.x;
    int wid = t >> 6, lane = t & 63;
    int row = blockIdx.x * 4 + wid;   // < 394320
    const float4 h = *(const float4*)(F + OFF_H + lane * 4);
    const float4 w = *(const float4*)(Wh3 + (size_t)row * 256 + lane * 4);
    float d = w.x * h.x + w.y * h.y + w.z * h.z + w.w * h.w;
    for (int off = 32; off; off >>= 1) d += __shfl_down(d, off);
    if (lane == 0) {
        float val = d + bh3[row];
        int s = row / TOTALP;
        int r = row - s * TOTALP;
        __hip_bfloat16* W1B = (__hip_bfloat16*)(F + OFF_W1B);
        __hip_bfloat16* W2B = (__hip_bfloat16*)(F + OFF_W2B);
        if (r < WS1P) {
            int hh = r >> 9, k = r & 511;
            W1B[(s * HID + hh) * DIM + k] = __float2bfloat16(val);
        } else if (r < WS1B1) {
            F[OFF_B1 + s * HID + (r - WS1P)] = val;
        } else if (r < WS2END) {
            int q = r - WS1B1; int c = q >> 5, hh = q & 31;
            float ws = F[OFF_W + s];
            W2B[c * NHID + s * HID + hh] = __float2bfloat16(ws * val);
        } else {
            F[OFF_B2R + s * NCLS + (r - WS2END)] = val;
        }
    }
}

// ---------------- K5: MFMA bf16 GEMM, C = act(A @ Bw^T + bias) ----------------
// BM = MR*64 rows per block, BN = 128, BK = 64. global_load_lds staging with
// pre-swizzled global source (linear LDS dest), XOR-swizzled ds_read.
// EPI=0: C bf16 ld 640, relu, bias = f32 array (b1).
// EPI=1: C f32 ld 100, col<100 mask, bias computed from ws (OFF_W x OFF_B2R).
template<int EPI, int MR>
__global__ __launch_bounds__(256) void gemm_k(
    const __hip_bfloat16* __restrict__ A, const __hip_bfloat16* __restrict__ Bw,
    const float* __restrict__ bias, void* __restrict__ Cp, int K, int lda, int nBN)
{
    __shared__ __align__(16) unsigned char sA[MR * 64 * 128];
    __shared__ __align__(16) unsigned char sB[128 * 128];
    const int t = threadIdx.x;
    // XCD-chunked swizzle (grid divisible by 8)
    int bid = blockIdx.x;
    const int cpx = gridDim.x >> 3;
    bid = (bid & 7) * cpx + (bid >> 3);
    const int bm = bid / nBN, bn = bid % nBN;
    const int Row0 = bm * (MR * 64), Col0 = bn * 128;
    const int wid = t >> 6, lane = t & 63;
    const int l16 = lane & 15, lq = lane >> 4;

    f32x4 acc[MR][8];
    #pragma unroll
    for (int a = 0; a < MR; ++a)
        #pragma unroll
        for (int b = 0; b < 8; ++b)
            acc[a][b] = (f32x4){0.f, 0.f, 0.f, 0.f};

    for (int kc = 0; kc < K; kc += 64) {
        __syncthreads();
        // A tile: MR*64 rows x 64 k, linear LDS, inverse-swizzled global source
        #pragma unroll
        for (int i = 0; i < MR * 2; ++i) {
            int cidx = wid * (MR * 2) + i;
            int ul = cidx * 64 + lane;
            int row = ul >> 3, u = ul & 7;
            const __hip_bfloat16* src =
                A + (size_t)(Row0 + row) * lda + kc + ((u ^ (row & 7)) << 3);
            gload16(src, sA + cidx * 1024);
        }
        // B tile: 128 rows x 64 k
        #pragma unroll
        for (int i = 0; i < 4; ++i) {
            int cidx = wid * 4 + i;
            int ul = cidx * 64 + lane;
            int row = ul >> 3, u = ul & 7;
            const __hip_bfloat16* src =
                Bw + (size_t)(Col0 + row) * K + kc + ((u ^ (row & 7)) << 3);
            gload16(src, sB + cidx * 1024);
        }
        __syncthreads();

        #pragma unroll
        for (int kk = 0; kk < 2; ++kk) {
            const int u = kk * 4 + lq;
            short8 af[MR], bfv[8];
            #pragma unroll
            for (int fm = 0; fm < MR; ++fm) {
                int row = wid * (MR * 16) + fm * 16 + l16;
                af[fm] = *(const short8*)(sA + row * 128 + ((u ^ (row & 7)) << 4));
            }
            #pragma unroll
            for (int fn = 0; fn < 8; ++fn) {
                int rw = fn * 16 + l16;
                bfv[fn] = *(const short8*)(sB + rw * 128 + ((u ^ (rw & 7)) << 4));
            }
            #pragma unroll
            for (int fm = 0; fm < MR; ++fm)
                #pragma unroll
                for (int fn = 0; fn < 8; ++fn)
                    acc[fm][fn] = __builtin_amdgcn_mfma_f32_16x16x32_bf16(
                        af[fm], bfv[fn], acc[fm][fn], 0, 0, 0);
        }
    }

    // per-thread bias for the 8 fn columns
    float bvv[8];
    #pragma unroll
    for (int fn = 0; fn < 8; ++fn) {
        int gcol = Col0 + fn * 16 + l16;
        if (EPI == 0) {
            bvv[fn] = bias[gcol];
        } else {
            float b = 0.f;
            if (gcol < NCLS)
                #pragma unroll
                for (int s = 0; s < NSUB; ++s)
                    b += bias[OFF_W + s] * bias[OFF_B2R + s * NCLS + gcol];
            bvv[fn] = b;
        }
    }

    #pragma unroll
    for (int fm = 0; fm < MR; ++fm) {
        #pragma unroll
        for (int fn = 0; fn < 8; ++fn) {
            int gcol = Col0 + fn * 16 + l16;
            #pragma unroll
            for (int r = 0; r < 4; ++r) {
                int grow = Row0 + wid * (MR * 16) + fm * 16 + lq * 4 + r;
                float v = acc[fm][fn][r] + bvv[fn];
                if (EPI == 0) {
                    v = fmaxf(v, 0.f);
                    ((__hip_bfloat16*)Cp)[(size_t)grow * NHID + gcol] = __float2bfloat16(v);
                } else {
                    if (gcol < NCLS)
                        ((float*)Cp)[(size_t)grow * NCLS + gcol] = v;
                }
            }
        }
    }
}

// ---------------- launch ----------------
extern "C" void kernel_launch(void* const* d_in, const int* in_sizes, int n_in,
                              void* d_out, int out_size, void* d_ws, size_t ws_size,
                              hipStream_t stream)
{
    const float* x    = (const float*)d_in[0];
    const float* Wh1  = (const float*)d_in[1];
    const float* bh1  = (const float*)d_in[2];
    const float* g1   = (const float*)d_in[3];
    const float* be1  = (const float*)d_in[4];
    const float* Wh2  = (const float*)d_in[5];
    const float* bh2  = (const float*)d_in[6];
    const float* g2   = (const float*)d_in[7];
    const float* be2  = (const float*)d_in[8];
    const float* Wh3  = (const float*)d_in[9];
    const float* bh3  = (const float*)d_in[10];
    const float* ensw = (const float*)d_in[11];
    float* F = (float*)d_ws;
    float* out = (float*)d_out;

    const __hip_bfloat16* XB  = (const __hip_bfloat16*)(F + OFF_XB);
    const __hip_bfloat16* W1B = (const __hip_bfloat16*)(F + OFF_W1B);
    const __hip_bfloat16* W2B = (const __hip_bfloat16*)(F + OFF_W2B);
    __hip_bfloat16* HH = (__hip_bfloat16*)(F + OFF_HH);

    // zero the atomic accumulator + counter (graph-capturable stream memset)
    hipMemsetAsync(F + OFF_CTX, 0, (512 + 16) * sizeof(float), stream);

    k1_fused<<<256, 256, 0, stream>>>(x, Wh1, bh1, g1, be1, Wh2, bh2, g2, be2, ensw, F);
    k3_gemv<<<NPAR / 4, 256, 0, stream>>>(Wh3, bh3, F);
    // stage 1: HH = relu(xb @ W1all^T + b1all)   M=32768 N=640 K=512
    gemm_k<0, 2><<<(BATCH / 128) * 5, 256, 0, stream>>>(XB, W1B, F + OFF_B1, HH, 512, 512, 5);
    // stage 2: out = HH @ W2eff^T + bias(ws)     M=32768 N=128(pad) K=640
    gemm_k<1, 1><<<(BATCH / 64), 256, 0, stream>>>(HH, W2B, F, out, 640, 640, 1);
}

// Round 5
// 222.366 us; speedup vs baseline: 1.1771x; 1.0951x over previous
//
#include <hip/hip_runtime.h>
#include <hip/hip_bf16.h>

// ---------------- problem constants ----------------
#define BATCH   32768
#define DIM     512
#define H1N     128
#define H2N     256
#define NSUB    20
#define HID     32
#define NCLS    100
#define NHID    640            // NSUB*HID
#define TOTALP  19716          // 512*32 + 32 + 32*100 + 100
#define NPAR    394320         // NSUB*TOTALP
#define WS1P    16384
#define WS1B1   16416          // WS1+BS1
#define WS2END  19616          // WS1+BS1+WS2

// ---------------- ws layout (float units) — R2 anchor ----------------
#define OFF_PART 0              // 256*512 partial col sums
#define OFF_H    131584         // 256 f32 hypernet h
#define OFF_W    131840         // 32 f32 softmax(ens_w)
#define OFF_B1   131872         // 640 f32
#define OFF_BE   132512         // 128 f32
#define OFF_B2R  132640         // 2000 f32 raw b2
#define OFF_W1B  134640         // bf16 640*512   (163840 f32 slots)
#define OFF_W2B  298480         // bf16 128*640   (40960 f32 slots)
#define OFF_XB   339440         // bf16 32768*512 (8388608 f32 slots)

typedef __attribute__((ext_vector_type(8))) short short8;
typedef __attribute__((ext_vector_type(4))) float f32x4;

static __device__ inline unsigned short f2bf(float f) {
    __hip_bfloat16 h = __float2bfloat16(f);
    return *reinterpret_cast<unsigned short*>(&h);
}

static __device__ __forceinline__ void gload16(const void* g, void* l) {
    __builtin_amdgcn_global_load_lds(
        (const __attribute__((address_space(1))) void*)g,
        (__attribute__((address_space(3))) void*)l, 16, 0, 0);
}

// ---------------- K1: partial column sums + bf16 convert of x (R2) ----------
__global__ __launch_bounds__(256) void k1_colsum(const float* __restrict__ x,
                                                 float* __restrict__ F) {
    int t = threadIdx.x, bid = blockIdx.x;
    const float* xb = x + (size_t)bid * 128 * DIM;
    unsigned short* ob = (unsigned short*)(F + OFF_XB) + (size_t)bid * 128 * DIM;
    float a0 = 0.f, a1 = 0.f;
    for (int r = 0; r < 128; ++r) {
        float2 v = *(const float2*)(xb + r * DIM + t * 2);
        a0 += v.x; a1 += v.y;
        ushort2 u; u.x = f2bf(v.x); u.y = f2bf(v.y);
        *(ushort2*)(ob + r * DIM + t * 2) = u;
    }
    *(float2*)(F + OFF_PART + bid * DIM + t * 2) = make_float2(a0, a1);
}

// ---------------- K2: hypernet trunk (1 block) (R2) ----------
__global__ __launch_bounds__(256) void k2_hyper(
    const float* __restrict__ Wh1, const float* __restrict__ bh1,
    const float* __restrict__ g1,  const float* __restrict__ be1,
    const float* __restrict__ Wh2, const float* __restrict__ bh2,
    const float* __restrict__ g2,  const float* __restrict__ be2,
    const float* __restrict__ ensw, float* __restrict__ F)
{
    __shared__ __align__(16) float sctx[DIM];
    __shared__ __align__(16) float sh1[H1N];
    __shared__ __align__(16) float sh2[H2N];
    int t = threadIdx.x;

    for (int c = t; c < DIM; c += 256) {
        float s = 0.f;
        for (int b = 0; b < 256; ++b) s += F[OFF_PART + b * DIM + c];
        sctx[c] = s * (1.0f / (float)BATCH);
    }
    __syncthreads();

    if (t < H1N) {
        float v = bh1[t];
        const float4* w = (const float4*)(Wh1 + t * DIM);
        for (int k = 0; k < DIM / 4; ++k) {
            float4 ww = w[k]; float4 c = *(const float4*)(sctx + k * 4);
            v += ww.x * c.x + ww.y * c.y + ww.z * c.z + ww.w * c.w;
        }
        sh1[t] = v;
    }
    __syncthreads();
    {
        float mu = 0.f;
        for (int k = 0; k < H1N; ++k) mu += sh1[k];
        mu *= (1.0f / H1N);
        float var = 0.f;
        for (int k = 0; k < H1N; ++k) { float d = sh1[k] - mu; var += d * d; }
        var *= (1.0f / H1N);
        float inv = rsqrtf(var + 1e-5f);
        __syncthreads();
        if (t < H1N) {
            float v = (sh1[t] - mu) * inv * g1[t] + be1[t];
            sh1[t] = fmaxf(v, 0.f);
        }
        __syncthreads();
    }

    {
        float v = bh2[t];
        const float4* w = (const float4*)(Wh2 + t * H1N);
        for (int k = 0; k < H1N / 4; ++k) {
            float4 ww = w[k]; float4 c = *(const float4*)(sh1 + k * 4);
            v += ww.x * c.x + ww.y * c.y + ww.z * c.z + ww.w * c.w;
        }
        sh2[t] = v;
    }
    __syncthreads();
    {
        float mu = 0.f;
        for (int k = 0; k < H2N; ++k) mu += sh2[k];
        mu *= (1.0f / H2N);
        float var = 0.f;
        for (int k = 0; k < H2N; ++k) { float d = sh2[k] - mu; var += d * d; }
        var *= (1.0f / H2N);
        float inv = rsqrtf(var + 1e-5f);
        float v = (sh2[t] - mu) * inv * g2[t] + be2[t];
        F[OFF_H + t] = fmaxf(v, 0.f);
    }

    if (t == 0) {
        float m = -1e30f;
        for (int s = 0; s < NSUB; ++s) m = fmaxf(m, ensw[s]);
        float sum = 0.f, e[NSUB];
        for (int s = 0; s < NSUB; ++s) { e[s] = __expf(ensw[s] - m); sum += e[s]; }
        for (int s = 0; s < NSUB; ++s) F[OFF_W + s] = e[s] / sum;
    }
}

// ---------------- K3: params GEMV fused with pack/convert (wave per row, R2) -
__global__ __launch_bounds__(256) void k3_gemv(
    const float* __restrict__ Wh3, const float* __restrict__ bh3, float* __restrict__ F)
{
    int t = threadIdx.x;
    int wid = t >> 6, lane = t & 63;
    int row = blockIdx.x * 4 + wid;   // < 394320
    const float4 h = *(const float4*)(F + OFF_H + lane * 4);
    const float4 w = *(const float4*)(Wh3 + (size_t)row * 256 + lane * 4);
    float d = w.x * h.x + w.y * h.y + w.z * h.z + w.w * h.w;
    for (int off = 32; off; off >>= 1) d += __shfl_down(d, off);
    if (lane == 0) {
        float val = d + bh3[row];
        int s = row / TOTALP;
        int r = row - s * TOTALP;
        __hip_bfloat16* W1B = (__hip_bfloat16*)(F + OFF_W1B);
        __hip_bfloat16* W2B = (__hip_bfloat16*)(F + OFF_W2B);
        if (r < WS1P) {
            int hh = r >> 9, k = r & 511;
            W1B[(s * HID + hh) * DIM + k] = __float2bfloat16(val);
        } else if (r < WS1B1) {
            F[OFF_B1 + s * HID + (r - WS1P)] = val;
        } else if (r < WS2END) {
            int q = r - WS1B1; int c = q >> 5, hh = q & 31;
            float ws = F[OFF_W + s];
            W2B[c * NHID + s * HID + hh] = __float2bfloat16(ws * val);
        } else {
            F[OFF_B2R + s * NCLS + (r - WS2END)] = val;
        }
    }
}

// ---------------- K4: b2 ensemble reduce (R2) ----------------
__global__ __launch_bounds__(128) void k4_be(float* __restrict__ F) {
    int t = threadIdx.x;
    float b = 0.f;
    if (t < NCLS)
        for (int s = 0; s < NSUB; ++s)
            b += F[OFF_W + s] * F[OFF_B2R + s * NCLS + t];
    F[OFF_BE + t] = b;
}

// ---------------- K5: fused dual GEMM ----------------
// Per block: 64 output rows. For each of 5 chunks of 128 HH-cols:
//   P = relu(XB_blk @ W1B_chunk^T + b1)  (K=512 MFMA loop, 128x64 sA/sB tiles)
//   P -> bf16 -> wave-private swizzled sP (64x128)
//   acc2 += P @ W2B_chunk^T              (K=128 in two 64-k sub-stages)
// out = acc2 + be, cols < 100. HH never touches global memory.
__global__ __launch_bounds__(256) void gemm_fused(
    const __hip_bfloat16* __restrict__ XB, const __hip_bfloat16* __restrict__ W1B,
    const __hip_bfloat16* __restrict__ W2B, const float* __restrict__ F,
    float* __restrict__ out)
{
    __shared__ __align__(16) unsigned char sA[64 * 128];    // 8 KB
    __shared__ __align__(16) unsigned char sB[128 * 128];   // 16 KB
    __shared__ __align__(16) unsigned char sP[64 * 256];    // 16 KB
    const int t = threadIdx.x;
    int bid = blockIdx.x;
    const int cpx = gridDim.x >> 3;
    bid = (bid & 7) * cpx + (bid >> 3);
    const int Row0 = bid * 64;
    const int wid = t >> 6, lane = t & 63;
    const int l16 = lane & 15, lq = lane >> 4;

    f32x4 acc2[8];
    #pragma unroll
    for (int fn = 0; fn < 8; ++fn) acc2[fn] = (f32x4){0.f, 0.f, 0.f, 0.f};

    for (int n1 = 0; n1 < 5; ++n1) {
        f32x4 acc1[8];
        #pragma unroll
        for (int fn = 0; fn < 8; ++fn) acc1[fn] = (f32x4){0.f, 0.f, 0.f, 0.f};

        for (int kc = 0; kc < 512; kc += 64) {
            __syncthreads();
            // A tile: 64 rows x 64 k
            #pragma unroll
            for (int i = 0; i < 2; ++i) {
                int cidx = wid * 2 + i;
                int ul = cidx * 64 + lane;
                int row = ul >> 3, u = ul & 7;
                gload16(XB + (size_t)(Row0 + row) * 512 + kc + ((u ^ (row & 7)) << 3),
                        sA + cidx * 1024);
            }
            // B1 tile: W1B rows n1*128..+128 x 64 k
            #pragma unroll
            for (int i = 0; i < 4; ++i) {
                int cidx = wid * 4 + i;
                int ul = cidx * 64 + lane;
                int row = ul >> 3, u = ul & 7;
                gload16(W1B + (size_t)(n1 * 128 + row) * 512 + kc + ((u ^ (row & 7)) << 3),
                        sB + cidx * 1024);
            }
            __syncthreads();
            #pragma unroll
            for (int kk = 0; kk < 2; ++kk) {
                int u = kk * 4 + lq;
                int arow = wid * 16 + l16;
                short8 af = *(const short8*)(sA + arow * 128 + ((u ^ (arow & 7)) << 4));
                short8 bfv[8];
                #pragma unroll
                for (int fn = 0; fn < 8; ++fn) {
                    int rw = fn * 16 + l16;
                    bfv[fn] = *(const short8*)(sB + rw * 128 + ((u ^ (rw & 7)) << 4));
                }
                #pragma unroll
                for (int fn = 0; fn < 8; ++fn)
                    acc1[fn] = __builtin_amdgcn_mfma_f32_16x16x32_bf16(
                        af, bfv[fn], acc1[fn], 0, 0, 0);
            }
        }

        // P = relu(acc1 + b1) -> bf16 -> sP (wave-private rows wid*16..+16)
        #pragma unroll
        for (int fn = 0; fn < 8; ++fn) {
            int col = fn * 16 + l16;
            float b1v = F[OFF_B1 + n1 * 128 + col];
            int unit = col >> 3;
            #pragma unroll
            for (int r = 0; r < 4; ++r) {
                int row = wid * 16 + lq * 4 + r;
                float v = fmaxf(acc1[fn][r] + b1v, 0.f);
                *(unsigned short*)(sP + row * 256 + ((unit ^ (row & 7)) << 4)
                                   + (col & 7) * 2) = f2bf(v);
            }
        }

        // stage-2: acc2 += P @ W2chunk^T (K = 128 in two 64-k halves)
        #pragma unroll
        for (int kk2 = 0; kk2 < 2; ++kk2) {
            __syncthreads();   // all waves done with sB stage-1 reads (and P written)
            #pragma unroll
            for (int i = 0; i < 4; ++i) {
                int cidx = wid * 4 + i;
                int ul = cidx * 64 + lane;
                int row = ul >> 3, u = ul & 7;
                gload16(W2B + (size_t)row * NHID + n1 * 128 + kk2 * 64
                            + ((u ^ (row & 7)) << 3),
                        sB + cidx * 1024);
            }
            __syncthreads();
            #pragma unroll
            for (int kk = 0; kk < 2; ++kk) {
                int u = kk * 4 + lq;
                int arow = wid * 16 + l16;
                int unit = kk2 * 8 + u;
                short8 af = *(const short8*)(sP + arow * 256 + ((unit ^ (arow & 7)) << 4));
                short8 bfv[8];
                #pragma unroll
                for (int fn = 0; fn < 8; ++fn) {
                    int rw = fn * 16 + l16;
                    bfv[fn] = *(const short8*)(sB + rw * 128 + ((u ^ (rw & 7)) << 4));
                }
                #pragma unroll
                for (int fn = 0; fn < 8; ++fn)
                    acc2[fn] = __builtin_amdgcn_mfma_f32_16x16x32_bf16(
                        af, bfv[fn], acc2[fn], 0, 0, 0);
            }
        }
    }

    // epilogue: out = acc2 + be, cols < 100
    #pragma unroll
    for (int fn = 0; fn < 8; ++fn) {
        int gcol = fn * 16 + l16;
        if (gcol < NCLS) {
            float be = F[OFF_BE + gcol];
            #pragma unroll
            for (int r = 0; r < 4; ++r) {
                int grow = Row0 + wid * 16 + lq * 4 + r;
                out[(size_t)grow * NCLS + gcol] = acc2[fn][r] + be;
            }
        }
    }
}

// ---------------- launch ----------------
extern "C" void kernel_launch(void* const* d_in, const int* in_sizes, int n_in,
                              void* d_out, int out_size, void* d_ws, size_t ws_size,
                              hipStream_t stream)
{
    const float* x    = (const float*)d_in[0];
    const float* Wh1  = (const float*)d_in[1];
    const float* bh1  = (const float*)d_in[2];
    const float* g1   = (const float*)d_in[3];
    const float* be1  = (const float*)d_in[4];
    const float* Wh2  = (const float*)d_in[5];
    const float* bh2  = (const float*)d_in[6];
    const float* g2   = (const float*)d_in[7];
    const float* be2  = (const float*)d_in[8];
    const float* Wh3  = (const float*)d_in[9];
    const float* bh3  = (const float*)d_in[10];
    const float* ensw = (const float*)d_in[11];
    float* F = (float*)d_ws;
    float* out = (float*)d_out;

    const __hip_bfloat16* XB  = (const __hip_bfloat16*)(F + OFF_XB);
    const __hip_bfloat16* W1B = (const __hip_bfloat16*)(F + OFF_W1B);
    const __hip_bfloat16* W2B = (const __hip_bfloat16*)(F + OFF_W2B);

    k1_colsum<<<256, 256, 0, stream>>>(x, F);
    k2_hyper<<<1, 256, 0, stream>>>(Wh1, bh1, g1, be1, Wh2, bh2, g2, be2, ensw, F);
    k3_gemv<<<NPAR / 4, 256, 0, stream>>>(Wh3, bh3, F);
    k4_be<<<1, 128, 0, stream>>>(F);
    // fused: out = relu(XB @ W1B^T + b1) @ W2B^T + be   M=32768, grid 512 x BM=64
    gemm_fused<<<BATCH / 64, 256, 0, stream>>>(XB, W1B, W2B, F, out);
}